// Round 2
// baseline (300.726 us; speedup 1.0000x reference)
//
#include <hip/hip_runtime.h>
#include <cmath>

#define Bdim 16
#define Sdim 16
#define Edim 256
#define Hdim 512
#define Vdim 16000
#define THR1f 0.8f
#define THR2f 1.0f

// ---------------------------------------------------------------------------
// Kernel 1: embedding gather + cur1 = emb@fc1_w.T + fc1_b  + m1 (Leaky) sim.
// Produces A[r][h], r = (t*16+b)*2 + {0:c_s, 1:c_m}, and final mem1.
//   c_s[h] = sum_u 0.9^{T-1-u} * spk1_u[h]
//   c_m[h] = sum_u wm_u * spk1_u[h],  wm_u = 10*(0.9^{T-u} - 0.8^{T-u})
// One block per batch b (16 blocks x 512 threads; thread = h).
// ---------------------------------------------------------------------------
__global__ __launch_bounds__(512) void snn_prep(
    const int* __restrict__ x, const float* __restrict__ embed_w,
    const float* __restrict__ fc1_w, const float* __restrict__ fc1_b,
    const float* __restrict__ beta1p, const int* __restrict__ tsp,
    float* __restrict__ Amat, float* __restrict__ mem1_out)
{
  __shared__ float emb_s[Sdim][Edim];   // 16 KB
  __shared__ float fw_s[32][513];       // ~65.7 KB, padded: conflict-free r/w
  const int b = blockIdx.x;
  const int h = threadIdx.x;

  // stage this batch's 16 embedding rows
  for (int k = h; k < Sdim * Edim; k += Hdim) {
    int t = k >> 8, e = k & 255;
    emb_s[t][e] = embed_w[(size_t)x[b * Sdim + t] * Edim + e];
  }

  float acc[Sdim];
#pragma unroll
  for (int t = 0; t < Sdim; ++t) acc[t] = 0.f;

  // cur1[t][h] for all 16 tokens; fc1_w staged in 32-wide e-tiles as [e][h]
  for (int e0 = 0; e0 < Edim; e0 += 32) {
    __syncthreads();
#pragma unroll
    for (int i = 0; i < 32; ++i) {
      int k = h + i * Hdim;
      int hh = k >> 5, j = k & 31;
      fw_s[j][hh] = fc1_w[hh * Edim + e0 + j];   // coalesced 32-float runs
    }
    __syncthreads();
#pragma unroll
    for (int j = 0; j < 32; ++j) {
      float w = fw_s[j][h];                      // conflict-free
#pragma unroll
      for (int t = 0; t < Sdim; ++t)
        acc[t] = fmaf(w, emb_s[t][e0 + j], acc[t]);  // emb broadcast
    }
  }

  const float bias = fc1_b[h];
  const float b1 = fminf(fmaxf(beta1p[0], 0.f), 1.f);
  const int T = tsp[0];

  double w9T = 1.0, w8T = 1.0;
  for (int i = 0; i < T; ++i) { w9T *= 0.9; w8T *= 0.8; }

  float m1 = 0.f;
  for (int t = 0; t < Sdim; ++t) {
    const float cur = acc[t] + bias;
    double p9 = w9T, p8 = w8T;    // 0.9^{T-u}, 0.8^{T-u} at u=0
    float cs = 0.f, cm = 0.f;
    for (int u = 0; u < T; ++u) {
      float reset = (m1 > THR1f) ? THR1f : 0.f;  // spike from previous mem
      m1 = b1 * m1 + cur - reset;
      if (m1 > THR1f) {                          // spk1
        cs += (float)(p9 * (10.0 / 9.0));        // 0.9^{T-1-u}
        cm += (float)(10.0 * (p9 - p8));         // wm_u
      }
      p9 *= (10.0 / 9.0);  // /0.9
      p8 *= 1.25;          // /0.8 (exact)
    }
    const int r = (t * Bdim + b) * 2;
    Amat[(size_t)r * Hdim + h] = cs;
    Amat[(size_t)(r + 1) * Hdim + h] = cm;
  }
  mem1_out[b * Hdim + h] = m1;
}

// ---------------------------------------------------------------------------
// Kernel 2: C[r][v] = sum_h A[r][h] * fc2_w[v][h]   (M=512, N=16000, K=512)
// fp32, 64x64 tiles, 256 threads, 4x4 micro-tile, K-tile 32.
// ---------------------------------------------------------------------------
#define TM 64
#define TN 64
#define TKK 32

__global__ __launch_bounds__(256) void snn_gemm(
    const float* __restrict__ Amat, const float* __restrict__ W,
    float* __restrict__ C)
{
  __shared__ __align__(16) float As[TKK][TM + 4];  // [h][r], 68-float rows
  __shared__ __align__(16) float Ws[TKK][TN + 4];  // [h][v]
  const int v0 = blockIdx.x * TN;
  const int r0 = blockIdx.y * TM;
  const int tid = threadIdx.x;
  const int tx = tid & 15, ty = tid >> 4;

  float acc[4][4] = {{0.f}};

  for (int k0 = 0; k0 < Hdim; k0 += TKK) {
    __syncthreads();
#pragma unroll
    for (int i = 0; i < 8; ++i) {
      int k = tid + i * 256;
      int rr = k >> 5, j = k & 31;
      As[j][rr] = Amat[(size_t)(r0 + rr) * Hdim + k0 + j];
    }
#pragma unroll
    for (int i = 0; i < 8; ++i) {
      int k = tid + i * 256;
      int vv = k >> 5, j = k & 31;
      Ws[j][vv] = W[(size_t)(v0 + vv) * Hdim + k0 + j];
    }
    __syncthreads();
#pragma unroll
    for (int j = 0; j < TKK; ++j) {
      const float4 av = *reinterpret_cast<const float4*>(&As[j][ty * 4]);
      const float4 wv = *reinterpret_cast<const float4*>(&Ws[j][tx * 4]);
      const float a[4] = {av.x, av.y, av.z, av.w};
      const float w[4] = {wv.x, wv.y, wv.z, wv.w};
#pragma unroll
      for (int i = 0; i < 4; ++i)
#pragma unroll
        for (int jj = 0; jj < 4; ++jj)
          acc[i][jj] = fmaf(a[i], w[jj], acc[i][jj]);
    }
  }

#pragma unroll
  for (int i = 0; i < 4; ++i) {
    float4 o = {acc[i][0], acc[i][1], acc[i][2], acc[i][3]};
    *reinterpret_cast<float4*>(&C[(size_t)(r0 + ty * 4 + i) * Vdim + v0 + tx * 4]) = o;
  }
}

// ---------------------------------------------------------------------------
// Kernel 3: per-(b,v) 16-token linear recurrence on (s2, m2); emits spikes.
//   s2' = 0.9^T s2 + Gs + fc2_b*Sws
//   m2' = 0.8^T m2 + 0.9*wm_0*s2 + Gm + fc2_b*Swm ; out = (m2' > 1)
// ---------------------------------------------------------------------------
__global__ __launch_bounds__(256) void snn_epi(
    const float* __restrict__ C, const float* __restrict__ fc2_b,
    const int* __restrict__ tsp,
    float* __restrict__ out, float* __restrict__ syn2, float* __restrict__ mem2)
{
  const int id = blockIdx.x * 256 + threadIdx.x;
  if (id >= Bdim * Vdim) return;
  const int v = id % Vdim;
  const int b = id / Vdim;
  const int T = tsp[0];

  double p9 = 1.0, p8 = 1.0;
  for (int i = 0; i < T; ++i) { p9 *= 0.9; p8 *= 0.8; }
  const float Ps  = (float)p9;                       // 0.9^T
  const float Pm  = (float)p8;                       // 0.8^T
  const float Pms = (float)(0.9 * 10.0 * (p9 - p8)); // 0.9 * wm_0
  const float Sws = (float)(10.0 * (1.0 - p9));
  const float Swm = (float)(10.0 * (9.0 * (1.0 - p9) - 4.0 * (1.0 - p8)));

  const float bb  = fc2_b[v];
  const float bbs = bb * Sws;
  const float bbm = bb * Swm;

  float s2 = 0.f, m2 = 0.f;
#pragma unroll
  for (int t = 0; t < Sdim; ++t) {
    const size_t r = (size_t)(t * Bdim + b) * 2;
    const float gs = C[r * Vdim + v];
    const float gm = C[(r + 1) * Vdim + v];
    const float m2n = Pm * m2 + Pms * s2 + gm + bbm;  // uses pre-update s2
    s2 = Ps * s2 + gs + bbs;
    m2 = m2n;
    out[((size_t)b * Sdim + t) * Vdim + v] = (m2 > THR2f) ? 1.f : 0.f;
  }
  syn2[(size_t)b * Vdim + v] = s2;
  mem2[(size_t)b * Vdim + v] = m2;
}

// ---------------------------------------------------------------------------
extern "C" void kernel_launch(void* const* d_in, const int* in_sizes, int n_in,
                              void* d_out, int out_size, void* d_ws, size_t ws_size,
                              hipStream_t stream) {
  const int*   x       = (const int*)d_in[0];
  const float* embed_w = (const float*)d_in[1];
  const float* fc1_w   = (const float*)d_in[2];
  const float* fc1_b   = (const float*)d_in[3];
  const float* fc2_w   = (const float*)d_in[4];
  const float* fc2_b   = (const float*)d_in[5];
  const float* beta1   = (const float*)d_in[6];
  const int*   tsteps  = (const int*)d_in[7];

  float* out  = (float*)d_out;                          // [16][16][16000]
  float* mem1 = out + (size_t)Bdim * Sdim * Vdim;       // [16][512]
  float* syn2 = mem1 + (size_t)Bdim * Hdim;             // [16][16000]
  float* mem2 = syn2 + (size_t)Bdim * Vdim;             // [16][16000]

  float* Amat = (float*)d_ws;                           // [512][512]   1 MB
  float* C    = Amat + (size_t)2 * Sdim * Bdim * Hdim;  // [512][16000] 32.8 MB

  snn_prep<<<Bdim, Hdim, 0, stream>>>(x, embed_w, fc1_w, fc1_b, beta1, tsteps,
                                      Amat, mem1);
  dim3 g(Vdim / TN, (2 * Sdim * Bdim) / TM);
  snn_gemm<<<g, 256, 0, stream>>>(Amat, fc2_w, C);
  snn_epi<<<(Bdim * Vdim + 255) / 256, 256, 0, stream>>>(C, fc2_b, tsteps,
                                                         out, syn2, mem2);
}

// Round 4
// 158.521 us; speedup vs baseline: 1.8971x; 1.8971x over previous
//
#include <hip/hip_runtime.h>

#define Bdim 16
#define Sdim 16
#define Edim 256
#define Hdim 512
#define Vdim 16000
#define THR1f 0.8f
#define THR2f 1.0f

typedef unsigned int   u32;
typedef unsigned short u16;
typedef __attribute__((ext_vector_type(8))) short bf16x8;
typedef __attribute__((ext_vector_type(4))) float f32x4;

__device__ __forceinline__ u16 f2bf(float f) {          // RNE fp32->bf16
  u32 u = __float_as_uint(f);
  return (u16)((u + 0x7FFFu + ((u >> 16) & 1u)) >> 16);
}
__device__ __forceinline__ float bf2f(u16 u) {
  return __uint_as_float(((u32)u) << 16);
}
__device__ __forceinline__ void gload16(const void* g, const void* lds) {
  __builtin_amdgcn_global_load_lds(
      (const __attribute__((address_space(1))) u32*)g,
      (__attribute__((address_space(3))) u32*)lds, 16, 0, 0);
}

// ---------------------------------------------------------------------------
// K0: fc2_w fp32 -> bf16 (8.192M elems, 8/thread, uint4 stores)
// ---------------------------------------------------------------------------
__global__ __launch_bounds__(256) void w2bf(const float* __restrict__ W,
                                            u16* __restrict__ Wb) {
  const size_t id = (size_t)blockIdx.x * 256 + threadIdx.x;  // 1,024,000
  const float4* s = (const float4*)W;
  const float4 a = s[id * 2], b = s[id * 2 + 1];
  uint4 o;
  o.x = (u32)f2bf(a.x) | ((u32)f2bf(a.y) << 16);
  o.y = (u32)f2bf(a.z) | ((u32)f2bf(a.w) << 16);
  o.z = (u32)f2bf(b.x) | ((u32)f2bf(b.y) << 16);
  o.w = (u32)f2bf(b.z) | ((u32)f2bf(b.w) << 16);
  ((uint4*)Wb)[id] = o;
}

// ---------------------------------------------------------------------------
// K1: cur1[r1=t*16+b][h] = emb_row(r1) @ fc1_w.T + fc1_b   (fp32, exact path)
// M=256, N=512, K=256; 64x64 tiles, TK=64, 256 thr, 4x4 micro. 32 blocks.
// ---------------------------------------------------------------------------
__global__ __launch_bounds__(256) void snn_cur1(
    const int* __restrict__ x, const float* __restrict__ embed_w,
    const float* __restrict__ fc1_w, const float* __restrict__ fc1_b,
    float* __restrict__ cur1)
{
  __shared__ __align__(16) float As[64][68];
  __shared__ __align__(16) float Ws[64][68];
  __shared__ int sidx[64];
  const int tid = threadIdx.x;
  const int n0 = blockIdx.x * 64, r0 = blockIdx.y * 64;
  const int tx = tid & 15, ty = tid >> 4;

  if (tid < 64) {
    const int r1 = r0 + tid;                 // r1 = t*16 + b
    sidx[tid] = x[(r1 & 15) * Sdim + (r1 >> 4)];
  }

  float acc[4][4] = {{0.f}};
  for (int k0 = 0; k0 < Edim; k0 += 64) {
    __syncthreads();                         // also covers sidx on iter 0
#pragma unroll
    for (int i = 0; i < 16; ++i) {
      const int k = tid + i * 256;
      const int rr = k >> 6, j = k & 63;
      As[j][rr] = embed_w[(size_t)sidx[rr] * Edim + k0 + j];
      Ws[j][rr] = fc1_w[(size_t)(n0 + rr) * Edim + k0 + j];
    }
    __syncthreads();
#pragma unroll
    for (int j = 0; j < 64; ++j) {
      const float4 av = *(const float4*)&As[j][ty * 4];
      const float4 wv = *(const float4*)&Ws[j][tx * 4];
      const float a[4] = {av.x, av.y, av.z, av.w};
      const float w[4] = {wv.x, wv.y, wv.z, wv.w};
#pragma unroll
      for (int i = 0; i < 4; ++i)
#pragma unroll
        for (int jj = 0; jj < 4; ++jj)
          acc[i][jj] = fmaf(a[i], w[jj], acc[i][jj]);
    }
  }
#pragma unroll
  for (int i = 0; i < 4; ++i) {
    float4 o;
    o.x = acc[i][0] + fc1_b[n0 + tx * 4 + 0];
    o.y = acc[i][1] + fc1_b[n0 + tx * 4 + 1];
    o.z = acc[i][2] + fc1_b[n0 + tx * 4 + 2];
    o.w = acc[i][3] + fc1_b[n0 + tx * 4 + 3];
    *(float4*)&cur1[(size_t)(r0 + ty * 4 + i) * Hdim + n0 + tx * 4] = o;
  }
}

// ---------------------------------------------------------------------------
// K2: per-(b,h) m1 recurrence (fp32, exact); emits A in bf16 + mem1.
//   A[(t*16+b)*2+0][h] = c_s,  A[...+1][h] = c_m
// ---------------------------------------------------------------------------
__global__ __launch_bounds__(256) void snn_rec(
    const float* __restrict__ cur1, const float* __restrict__ beta1p,
    const int* __restrict__ tsp, u16* __restrict__ Ab,
    float* __restrict__ mem1)
{
  const int id = blockIdx.x * 256 + threadIdx.x;   // 8192 threads
  const int b = id >> 9, h = id & 511;
  const float b1 = fminf(fmaxf(beta1p[0], 0.f), 1.f);
  const int T = tsp[0];

  double w9T = 1.0, w8T = 1.0;
  for (int i = 0; i < T; ++i) { w9T *= 0.9; w8T *= 0.8; }

  float m1 = 0.f;
  for (int t = 0; t < Sdim; ++t) {
    const float cur = cur1[(size_t)(t * Bdim + b) * Hdim + h];
    double p9 = w9T, p8 = w8T;                 // 0.9^{T-u}, 0.8^{T-u}
    float cs = 0.f, cm = 0.f;
    for (int u = 0; u < T; ++u) {
      const float reset = (m1 > THR1f) ? THR1f : 0.f;
      m1 = b1 * m1 + cur - reset;
      if (m1 > THR1f) {
        cs += (float)(p9 * (10.0 / 9.0));      // 0.9^{T-1-u}
        cm += (float)(10.0 * (p9 - p8));       // wm_u
      }
      p9 *= (10.0 / 9.0);
      p8 *= 1.25;
    }
    const size_t r = (size_t)(t * Bdim + b) * 2;
    Ab[r * Hdim + h]       = f2bf(cs);
    Ab[(r + 1) * Hdim + h] = f2bf(cm);
  }
  mem1[b * Hdim + h] = m1;
}

// ---------------------------------------------------------------------------
// K3: MFMA bf16 GEMM  C[r][v] = A[r][:] . W[v][:]   (M=512, N=16000, K=512)
// 128x128 tile, BK=64, 4 waves (2x2), 4x4 frags of 16x16x32.
// global_load_lds(16B) linear dest + pre-swizzled source; XOR-swizzled
// ds_read_b128 (byte ^= (row&7)<<4) kills the 16-way bank conflict.
// ---------------------------------------------------------------------------
__global__ __launch_bounds__(256) void snn_mfma(
    const u16* __restrict__ Ab, const u16* __restrict__ Wb,
    u16* __restrict__ Cb)
{
  __shared__ __align__(16) u16 As[128 * 64];
  __shared__ __align__(16) u16 Bs[128 * 64];
  const int tid  = threadIdx.x;
  const int lane = tid & 63;
  const int wid  = tid >> 6;
  const int wm   = wid >> 1, wn = wid & 1;
  const int v0 = blockIdx.x * 128;
  const int r0 = blockIdx.y * 128;

  f32x4 acc[4][4];
#pragma unroll
  for (int i = 0; i < 4; ++i)
#pragma unroll
    for (int j = 0; j < 4; ++j)
#pragma unroll
      for (int e = 0; e < 4; ++e) acc[i][j][e] = 0.f;

  char* AsB = (char*)As;
  char* BsB = (char*)Bs;

  for (int k0 = 0; k0 < Hdim; k0 += 64) {
    // stage 16KB A-tile + 16KB B-tile; linear LDS dest, swizzled global src
#pragma unroll
    for (int rnd = 0; rnd < 4; ++rnd) {
      const int base = (rnd * 4 + wid) << 10;       // wave-uniform LDS base
      const int flat = base + lane * 16;            // this lane's dest byte
      const int row  = flat >> 7;                   // 128 B per tile row
      const int cl   = (flat & 127) ^ ((row & 7) << 4);
      gload16(Ab + (((size_t)(r0 + row)) << 9) + k0 + (cl >> 1), AsB + base);
      gload16(Wb + (((size_t)(v0 + row)) << 9) + k0 + (cl >> 1), BsB + base);
    }
    __syncthreads();
#pragma unroll
    for (int kk = 0; kk < 2; ++kk) {
      const int cbase = kk * 64 + ((lane >> 4) << 4);
      bf16x8 af[4], bfr[4];
#pragma unroll
      for (int i = 0; i < 4; ++i) {
        const int ar = wm * 64 + i * 16 + (lane & 15);
        af[i]  = *(const bf16x8*)(AsB + ar * 128 + (cbase ^ ((ar & 7) << 4)));
        const int br = wn * 64 + i * 16 + (lane & 15);
        bfr[i] = *(const bf16x8*)(BsB + br * 128 + (cbase ^ ((br & 7) << 4)));
      }
#pragma unroll
      for (int mi = 0; mi < 4; ++mi)
#pragma unroll
        for (int ni = 0; ni < 4; ++ni)
          acc[mi][ni] = __builtin_amdgcn_mfma_f32_16x16x32_bf16(
              af[mi], bfr[ni], acc[mi][ni], 0, 0, 0);
    }
    __syncthreads();
  }

  // C/D layout: col = lane&15, row = (lane>>4)*4 + reg   [m89-verified]
  const int cn = lane & 15, rq = (lane >> 4) * 4;
#pragma unroll
  for (int mi = 0; mi < 4; ++mi) {
    const int rrow = r0 + wm * 64 + mi * 16 + rq;
#pragma unroll
    for (int ni = 0; ni < 4; ++ni) {
      const int ccol = v0 + wn * 64 + ni * 16 + cn;
#pragma unroll
      for (int e = 0; e < 4; ++e)
        Cb[(size_t)(rrow + e) * Vdim + ccol] = f2bf(acc[mi][ni][e]);
    }
  }
}

// ---------------------------------------------------------------------------
// K4: per-(b,v) 16-token linear recurrence on (s2,m2); emits spikes.
// ---------------------------------------------------------------------------
__global__ __launch_bounds__(256) void snn_epi(
    const u16* __restrict__ Cb, const float* __restrict__ fc2_b,
    const int* __restrict__ tsp,
    float* __restrict__ out, float* __restrict__ syn2, float* __restrict__ mem2)
{
  const int id = blockIdx.x * 256 + threadIdx.x;
  if (id >= Bdim * Vdim) return;
  const int v = id % Vdim;
  const int b = id / Vdim;
  const int T = tsp[0];

  double p9 = 1.0, p8 = 1.0;
  for (int i = 0; i < T; ++i) { p9 *= 0.9; p8 *= 0.8; }
  const float Ps  = (float)p9;                       // 0.9^T
  const float Pm  = (float)p8;                       // 0.8^T
  const float Pms = (float)(0.9 * 10.0 * (p9 - p8)); // s2-coeff into m2
  const float Sws = (float)(10.0 * (1.0 - p9));
  const float Swm = (float)(10.0 * (9.0 * (1.0 - p9) - 4.0 * (1.0 - p8)));

  const float bb  = fc2_b[v];
  const float bbs = bb * Sws;
  const float bbm = bb * Swm;

  float s2 = 0.f, m2 = 0.f;
#pragma unroll
  for (int t = 0; t < Sdim; ++t) {
    const size_t r = (size_t)(t * Bdim + b) * 2;
    const float gs = bf2f(Cb[r * Vdim + v]);
    const float gm = bf2f(Cb[(r + 1) * Vdim + v]);
    const float m2n = Pm * m2 + Pms * s2 + gm + bbm;
    s2 = Ps * s2 + gs + bbs;
    m2 = m2n;
    out[((size_t)b * Sdim + t) * Vdim + v] = (m2 > THR2f) ? 1.f : 0.f;
  }
  syn2[(size_t)b * Vdim + v] = s2;
  mem2[(size_t)b * Vdim + v] = m2;
}

// ---------------------------------------------------------------------------
extern "C" void kernel_launch(void* const* d_in, const int* in_sizes, int n_in,
                              void* d_out, int out_size, void* d_ws, size_t ws_size,
                              hipStream_t stream) {
  const int*   x       = (const int*)d_in[0];
  const float* embed_w = (const float*)d_in[1];
  const float* fc1_w   = (const float*)d_in[2];
  const float* fc1_b   = (const float*)d_in[3];
  const float* fc2_w   = (const float*)d_in[4];
  const float* fc2_b   = (const float*)d_in[5];
  const float* beta1   = (const float*)d_in[6];
  const int*   tsteps  = (const int*)d_in[7];

  float* out  = (float*)d_out;                          // [16][16][16000]
  float* mem1 = out + (size_t)Bdim * Sdim * Vdim;       // [16][512]
  float* syn2 = mem1 + (size_t)Bdim * Hdim;             // [16][16000]
  float* mem2 = syn2 + (size_t)Bdim * Vdim;             // [16][16000]

  // ws layout (33,784,576 B total — under the proven round-2 ws footprint)
  float* cur1 = (float*)d_ws;                                   // 512 KB
  u16*   Ab   = (u16*)((char*)d_ws + 524288);                   // 512 KB
  u16*   Wb   = (u16*)((char*)d_ws + 1048576);                  // 16,384,000 B
  u16*   Cb   = (u16*)((char*)d_ws + 1048576 + 16384000);       // 16,384,000 B

  w2bf<<<4000, 256, 0, stream>>>(fc2_w, Wb);
  snn_cur1<<<dim3(Hdim / 64, (Sdim * Bdim) / 64), 256, 0, stream>>>(
      x, embed_w, fc1_w, fc1_b, cur1);
  snn_rec<<<(Bdim * Hdim) / 256, 256, 0, stream>>>(cur1, beta1, tsteps, Ab, mem1);
  snn_mfma<<<dim3(Vdim / 128, (2 * Sdim * Bdim) / 128), 256, 0, stream>>>(Ab, Wb, Cb);
  snn_epi<<<(Bdim * Vdim + 255) / 256, 256, 0, stream>>>(Cb, fc2_b, tsteps,
                                                         out, syn2, mem2);
}

// Round 5
// 156.350 us; speedup vs baseline: 1.9234x; 1.0139x over previous
//
#include <hip/hip_runtime.h>

#define Bdim 16
#define Sdim 16
#define Edim 256
#define Hdim 512
#define Vdim 16000
#define THR1f 0.8f
#define THR2f 1.0f

typedef unsigned int   u32;
typedef unsigned short u16;
typedef __attribute__((ext_vector_type(8))) short bf16x8;
typedef __attribute__((ext_vector_type(4))) float f32x4;

__device__ __forceinline__ u16 f2bf(float f) {          // RNE fp32->bf16
  u32 u = __float_as_uint(f);
  return (u16)((u + 0x7FFFu + ((u >> 16) & 1u)) >> 16);
}
__device__ __forceinline__ u32 pack2(float a, float b) {
  return (u32)f2bf(a) | ((u32)f2bf(b) << 16);
}
__device__ __forceinline__ void gload16(const void* g, const void* lds) {
  __builtin_amdgcn_global_load_lds(
      (const __attribute__((address_space(1))) u32*)g,
      (__attribute__((address_space(3))) u32*)lds, 16, 0, 0);
}

// ---------------------------------------------------------------------------
// K1: cur1[r1=t*16+b][h] = emb_row(r1) @ fc1_w.T + fc1_b   (fp32, exact path)
// M=256, N=512, K=256; 64x64 tiles, TK=64, 256 thr, 4x4 micro. 32 blocks.
// ---------------------------------------------------------------------------
__global__ __launch_bounds__(256) void snn_cur1(
    const int* __restrict__ x, const float* __restrict__ embed_w,
    const float* __restrict__ fc1_w, const float* __restrict__ fc1_b,
    float* __restrict__ cur1)
{
  __shared__ __align__(16) float As[64][68];
  __shared__ __align__(16) float Ws[64][68];
  __shared__ int sidx[64];
  const int tid = threadIdx.x;
  const int n0 = blockIdx.x * 64, r0 = blockIdx.y * 64;
  const int tx = tid & 15, ty = tid >> 4;

  if (tid < 64) {
    const int r1 = r0 + tid;                 // r1 = t*16 + b
    sidx[tid] = x[(r1 & 15) * Sdim + (r1 >> 4)];
  }

  float acc[4][4] = {{0.f}};
  for (int k0 = 0; k0 < Edim; k0 += 64) {
    __syncthreads();                         // also covers sidx on iter 0
#pragma unroll
    for (int i = 0; i < 16; ++i) {
      const int k = tid + i * 256;
      const int rr = k >> 6, j = k & 63;
      As[j][rr] = embed_w[(size_t)sidx[rr] * Edim + k0 + j];
      Ws[j][rr] = fc1_w[(size_t)(n0 + rr) * Edim + k0 + j];
    }
    __syncthreads();
#pragma unroll
    for (int j = 0; j < 64; ++j) {
      const float4 av = *(const float4*)&As[j][ty * 4];
      const float4 wv = *(const float4*)&Ws[j][tx * 4];
      const float a[4] = {av.x, av.y, av.z, av.w};
      const float w[4] = {wv.x, wv.y, wv.z, wv.w};
#pragma unroll
      for (int i = 0; i < 4; ++i)
#pragma unroll
        for (int jj = 0; jj < 4; ++jj)
          acc[i][jj] = fmaf(a[i], w[jj], acc[i][jj]);
    }
  }
#pragma unroll
  for (int i = 0; i < 4; ++i) {
    float4 o;
    o.x = acc[i][0] + fc1_b[n0 + tx * 4 + 0];
    o.y = acc[i][1] + fc1_b[n0 + tx * 4 + 1];
    o.z = acc[i][2] + fc1_b[n0 + tx * 4 + 2];
    o.w = acc[i][3] + fc1_b[n0 + tx * 4 + 3];
    *(float4*)&cur1[(size_t)(r0 + ty * 4 + i) * Hdim + n0 + tx * 4] = o;
  }
}

// ---------------------------------------------------------------------------
// K2: per-(b,h) m1 recurrence (fp32, exact); emits A in bf16 + mem1.
//   A[(t*16+b)*2+0][h] = c_s,  A[...+1][h] = c_m
// ---------------------------------------------------------------------------
__global__ __launch_bounds__(256) void snn_rec(
    const float* __restrict__ cur1, const float* __restrict__ beta1p,
    const int* __restrict__ tsp, u16* __restrict__ Ab,
    float* __restrict__ mem1)
{
  const int id = blockIdx.x * 256 + threadIdx.x;   // 8192 threads
  const int b = id >> 9, h = id & 511;
  const float b1 = fminf(fmaxf(beta1p[0], 0.f), 1.f);
  const int T = tsp[0];

  double w9T = 1.0, w8T = 1.0;
  for (int i = 0; i < T; ++i) { w9T *= 0.9; w8T *= 0.8; }

  float m1 = 0.f;
  for (int t = 0; t < Sdim; ++t) {
    const float cur = cur1[(size_t)(t * Bdim + b) * Hdim + h];
    double p9 = w9T, p8 = w8T;                 // 0.9^{T-u}, 0.8^{T-u}
    float cs = 0.f, cm = 0.f;
    for (int u = 0; u < T; ++u) {
      const float reset = (m1 > THR1f) ? THR1f : 0.f;
      m1 = b1 * m1 + cur - reset;
      if (m1 > THR1f) {
        cs += (float)(p9 * (10.0 / 9.0));      // 0.9^{T-1-u}
        cm += (float)(10.0 * (p9 - p8));       // wm_u
      }
      p9 *= (10.0 / 9.0);
      p8 *= 1.25;
    }
    const size_t r = (size_t)(t * Bdim + b) * 2;
    Ab[r * Hdim + h]       = f2bf(cs);
    Ab[(r + 1) * Hdim + h] = f2bf(cm);
  }
  mem1[b * Hdim + h] = m1;
}

// ---------------------------------------------------------------------------
// K3: fused MFMA GEMM + Synaptic recurrence + spike output.
// Tile: M=512 (ALL rows) x N=64 cols, 4 waves, wave owns 16 cols.
// acc[mi], mi=0..31: frag rows mi*16..mi*16+15. Lane (g=lane>>4) holds
// rows mi*16+g*4+e. With r=32t+2b+c: lane g owns b in {2g,2g+1,2g+8,2g+9};
//   gs(t,b=hi*8+2g+j) = acc[2t+hi][2j], gm = acc[2t+hi][2j+1].
// -> entire (s2,m2) recurrence is in-register; no C buffer, no epi kernel.
// A (bf16, L2-resident, identical for all blocks): global_load_lds(16B),
// linear dest + pre-swizzled source. W (fp32, read once from HBM):
// reg-staged with inline fp32->bf16 convert, swizzled ds_write_b128.
// Both read back with byte ^= (row&7)<<4 (kills 16-way bank conflict).
// ---------------------------------------------------------------------------
__global__ __launch_bounds__(256) void snn_fused(
    const u16* __restrict__ Ab, const float* __restrict__ W,
    const float* __restrict__ fc2_b, const int* __restrict__ tsp,
    float* __restrict__ out, float* __restrict__ syn2, float* __restrict__ mem2)
{
  __shared__ __align__(16) u16 As[512 * 64];   // 64 KB
  __shared__ __align__(16) u16 Bs[64 * 64];    //  8 KB
  const int tid  = threadIdx.x;
  const int lane = tid & 63;
  const int wid  = tid >> 6;
  const int v0   = blockIdx.x * 64;

  f32x4 acc[32];
#pragma unroll
  for (int i = 0; i < 32; ++i)
#pragma unroll
    for (int e = 0; e < 4; ++e) acc[i][e] = 0.f;

  char* AsB = (char*)As;
  char* BsB = (char*)Bs;

  // W staging geometry (per k-step): 64 rows x 64 k; thread -> 16 elems.
  const int brow = tid >> 2;             // 0..63
  const int bkc  = (tid & 3) * 16;       // elem col
  const int bswz = (brow & 7) << 4;

  for (int k0 = 0; k0 < Hdim; k0 += 64) {
    // --- A: 64 KB via global_load_lds, 16 rounds of 4 KB ---
#pragma unroll
    for (int rnd = 0; rnd < 16; ++rnd) {
      const int base = rnd * 4096 + wid * 1024;     // wave-uniform
      const int flat = base + lane * 16;
      const int row  = flat >> 7;                   // 128 B per row
      const int cl   = (flat & 127) ^ ((row & 7) << 4);
      gload16(Ab + ((size_t)row << 9) + k0 + (cl >> 1), AsB + base);
    }
    // --- B: 8 KB reg-staged, fp32 W -> bf16, swizzled ds_write ---
    {
      const float4* wp =
          (const float4*)&W[(size_t)(v0 + brow) * Hdim + k0 + bkc];
      const float4 w0 = wp[0], w1 = wp[1], w2 = wp[2], w3 = wp[3];
      uint4 o0, o1;
      o0.x = pack2(w0.x, w0.y); o0.y = pack2(w0.z, w0.w);
      o0.z = pack2(w1.x, w1.y); o0.w = pack2(w1.z, w1.w);
      o1.x = pack2(w2.x, w2.y); o1.y = pack2(w2.z, w2.w);
      o1.z = pack2(w3.x, w3.y); o1.w = pack2(w3.z, w3.w);
      const int cb = bkc * 2;                       // byte col (0,32,64,96)
      *(uint4*)(BsB + brow * 128 + (cb ^ bswz)) = o0;
      *(uint4*)(BsB + brow * 128 + ((cb + 16) ^ bswz)) = o1;
    }
    __syncthreads();
#pragma unroll
    for (int kk = 0; kk < 2; ++kk) {
      const int cbase = kk * 64 + ((lane >> 4) << 4);
      const int br = wid * 16 + (lane & 15);
      const bf16x8 bfr =
          *(const bf16x8*)(BsB + br * 128 + (cbase ^ ((br & 7) << 4)));
#pragma unroll
      for (int mi = 0; mi < 32; ++mi) {
        const int ar = mi * 16 + (lane & 15);
        const bf16x8 af =
            *(const bf16x8*)(AsB + ar * 128 + (cbase ^ ((ar & 7) << 4)));
        acc[mi] = __builtin_amdgcn_mfma_f32_16x16x32_bf16(af, bfr, acc[mi],
                                                          0, 0, 0);
      }
    }
    __syncthreads();
  }

  // ---- in-register Synaptic recurrence + spike emission ----
  const int T = tsp[0];
  double p9 = 1.0, p8 = 1.0;
  for (int i = 0; i < T; ++i) { p9 *= 0.9; p8 *= 0.8; }
  const float Ps  = (float)p9;                       // 0.9^T
  const float Pm  = (float)p8;                       // 0.8^T
  const float Pms = (float)(0.9 * 10.0 * (p9 - p8)); // s2-coeff into m2
  const float Sws = (float)(10.0 * (1.0 - p9));
  const float Swm = (float)(10.0 * (9.0 * (1.0 - p9) - 4.0 * (1.0 - p8)));

  const int g = lane >> 4;
  const int v = v0 + wid * 16 + (lane & 15);
  const float bb  = fc2_b[v];
  const float bbs = bb * Sws;
  const float bbm = bb * Swm;

#pragma unroll
  for (int hi = 0; hi < 2; ++hi) {
#pragma unroll
    for (int j = 0; j < 2; ++j) {
      const int b = hi * 8 + 2 * g + j;
      float s2 = 0.f, m2 = 0.f;
#pragma unroll
      for (int t = 0; t < Sdim; ++t) {
        const float gs = acc[2 * t + hi][2 * j];
        const float gm = acc[2 * t + hi][2 * j + 1];
        const float m2n = Pm * m2 + Pms * s2 + gm + bbm;
        s2 = Ps * s2 + gs + bbs;
        m2 = m2n;
        out[((size_t)b * Sdim + t) * Vdim + v] = (m2 > THR2f) ? 1.f : 0.f;
      }
      syn2[(size_t)b * Vdim + v] = s2;
      mem2[(size_t)b * Vdim + v] = m2;
    }
  }
}

// ---------------------------------------------------------------------------
extern "C" void kernel_launch(void* const* d_in, const int* in_sizes, int n_in,
                              void* d_out, int out_size, void* d_ws, size_t ws_size,
                              hipStream_t stream) {
  const int*   x       = (const int*)d_in[0];
  const float* embed_w = (const float*)d_in[1];
  const float* fc1_w   = (const float*)d_in[2];
  const float* fc1_b   = (const float*)d_in[3];
  const float* fc2_w   = (const float*)d_in[4];
  const float* fc2_b   = (const float*)d_in[5];
  const float* beta1   = (const float*)d_in[6];
  const int*   tsteps  = (const int*)d_in[7];

  float* out  = (float*)d_out;                          // [16][16][16000]
  float* mem1 = out + (size_t)Bdim * Sdim * Vdim;       // [16][512]
  float* syn2 = mem1 + (size_t)Bdim * Hdim;             // [16][16000]
  float* mem2 = syn2 + (size_t)Bdim * Vdim;             // [16][16000]

  // ws: cur1 512 KB + Ab 512 KB = 1 MB
  float* cur1 = (float*)d_ws;
  u16*   Ab   = (u16*)((char*)d_ws + 524288);

  snn_cur1<<<dim3(Hdim / 64, (Sdim * Bdim) / 64), 256, 0, stream>>>(
      x, embed_w, fc1_w, fc1_b, cur1);
  snn_rec<<<(Bdim * Hdim) / 256, 256, 0, stream>>>(cur1, beta1, tsteps, Ab, mem1);
  snn_fused<<<Vdim / 64, 256, 0, stream>>>(Ab, fc2_w, fc2_b, tsteps,
                                           out, syn2, mem2);
}